// Round 5
// baseline (441.119 us; speedup 1.0000x reference)
//
#include <hip/hip_runtime.h>

// ---------- helpers ----------
typedef __attribute__((ext_vector_type(8))) short short8;
typedef __attribute__((ext_vector_type(4))) float f32x4;

__device__ __forceinline__ unsigned short f2bf(float f) {
    union { float f; unsigned u; } v; v.f = f;
    unsigned r = v.u + 0x7FFFu + ((v.u >> 16) & 1u);   // RNE
    return (unsigned short)(r >> 16);
}
__device__ __forceinline__ float bf2f(unsigned short h) {
    union { unsigned u; float f; } v; v.u = ((unsigned)h) << 16;
    return v.f;
}

// fast tanh: 1 v_exp_f32 + 1 v_rcp_f32. rel err ~1e-5 << bf16 ulp.
__device__ __forceinline__ float tanh_fast(float x) {
    float xc = fminf(fmaxf(x, -9.0f), 9.0f);
    float t  = __expf(2.0f * xc);
    return (t - 1.0f) * __builtin_amdgcn_rcpf(t + 1.0f);
}

#define GLD16(gptr, lptr)                                                     \
    __builtin_amdgcn_global_load_lds(                                         \
        (const __attribute__((address_space(1))) unsigned int*)(gptr),        \
        (__attribute__((address_space(3))) unsigned int*)(lptr), 16, 0, 0)

// pack hi16(lo),hi16(hi) -> dword (bf16 truncation x2, 1 v_perm_b32)
__device__ __forceinline__ unsigned pk_trunc(float lo, float hi) {
    return __builtin_amdgcn_perm(__float_as_uint(hi), __float_as_uint(lo), 0x07060302u);
}

// ---------- merged weight cast: W1|W2|W3 f32 -> bf16 (RNE) ----------
__global__ __launch_bounds__(256) void cast_weights(
    const float* __restrict__ W1, const float* __restrict__ W2,
    const float* __restrict__ W3, unsigned short* __restrict__ w1bf,
    unsigned short* __restrict__ w2bf, unsigned short* __restrict__ w3bf)
{
    int t = (blockIdx.x * 256 + threadIdx.x) * 4;      // elems: 131072+131072+32768
    const float* s; unsigned short* d; int base;
    if (t < 131072)      { s = W1; d = w1bf; base = t; }
    else if (t < 262144) { s = W2; d = w2bf; base = t - 131072; }
    else if (t < 294912) { s = W3; d = w3bf; base = t - 262144; }
    else return;
    float4 v = *(const float4*)(s + base);
    unsigned long long p =
        (unsigned long long)f2bf(v.x)
      | ((unsigned long long)f2bf(v.y) << 16)
      | ((unsigned long long)f2bf(v.z) << 32)
      | ((unsigned long long)f2bf(v.w) << 48);
    *(unsigned long long*)(d + base) = p;
}

#define TM 128
#define TN 128
#define BK 64

// ---------- GEMM1: A f32 (x), B bf16 (W^T rows), C bf16, tanh fused ----------
// f32 A staged raw via global_load_lds; trunc->bf16 during fragment build.
__global__ __launch_bounds__(256) void gemm_a32_bt(
    const float* __restrict__ A, const unsigned short* __restrict__ B,
    const float* __restrict__ bias, unsigned short* __restrict__ C,
    int M, int N, int K)
{
    __shared__ __align__(16) float Asf[TM][BK];   // 32 KB
    __shared__ __align__(16) short Bs[TM][BK];    // 16 KB

    const int tid  = threadIdx.x;
    const int wave = tid >> 6;
    const int lane = tid & 63;
    const int m0 = blockIdx.x * TM;
    const int n0 = blockIdx.y * TN;
    const int wm = (wave >> 1) * 64;
    const int wn = (wave & 1) * 64;
    const int lm = lane & 15;
    const int quad = lane >> 4;

    // A staging: 16B chunk = 4 floats; row = 16 chunks. XOR-16 swizzle:
    // position p of row r holds global chunk p ^ (r & 15).
    const int srowA = lane >> 4;      // 0..3 (4 rows per GLD)
    const int lA    = lane & 15;
    // B staging: 16B chunk = 8 shorts; row = 8 chunks. XOR-8 swizzle.
    const int srowB = lane >> 3;      // 0..7
    const int cB    = ((lane & 7) ^ srowB) * 8;

    f32x4 acc[4][4] = {};

    for (int k0 = 0; k0 < K; k0 += BK) {
        #pragma unroll
        for (int i = 0; i < 8; ++i) {
            int row0 = wave * 32 + i * 4;
            int gr = m0 + row0 + srowA; if (gr >= M) gr = M - 1;
            int cA = lA ^ ((row0 + srowA) & 15);
            GLD16(A + (size_t)gr * K + k0 + cA * 4, &Asf[row0][0]);
        }
        #pragma unroll
        for (int i = 0; i < 4; ++i) {
            int row0 = wave * 32 + i * 8;
            GLD16(B + (size_t)(n0 + row0 + srowB) * K + k0 + cB, &Bs[row0][0]);
        }
        __syncthreads();

        #pragma unroll
        for (int ks = 0; ks < BK; ks += 32) {
            const int qb = ks >> 2;               // f32 16B-chunk base: 0 or 8
            const int ccB = (((ks >> 3) + quad) ^ (lm & 7)) * 8;
            short8 af[4], bfr[4];
            #pragma unroll
            for (int i = 0; i < 4; ++i) {
                const float* rowp = &Asf[wm + i * 16 + lm][0];
                float4 f0 = *(const float4*)(rowp + (((qb + quad * 2)     ) ^ lm) * 4);
                float4 f1 = *(const float4*)(rowp + (((qb + quad * 2) + 1) ^ lm) * 4);
                union { short8 s; uint4 u; } cv;
                cv.u.x = pk_trunc(f0.x, f0.y);
                cv.u.y = pk_trunc(f0.z, f0.w);
                cv.u.z = pk_trunc(f1.x, f1.y);
                cv.u.w = pk_trunc(f1.z, f1.w);
                af[i]  = cv.s;
                bfr[i] = *(const short8*)&Bs[wn + i * 16 + lm][ccB];
            }
            #pragma unroll
            for (int im = 0; im < 4; ++im)
                #pragma unroll
                for (int in = 0; in < 4; ++in)
                    acc[im][in] = __builtin_amdgcn_mfma_f32_16x16x32_bf16(
                        af[im], bfr[in], acc[im][in], 0, 0, 0);
        }
        __syncthreads();
    }

    #pragma unroll
    for (int im = 0; im < 4; ++im) {
        int gm_base = m0 + wm + im * 16 + quad * 4;
        #pragma unroll
        for (int in = 0; in < 4; ++in) {
            int gn = n0 + wn + in * 16 + lm;
            float bv = bias[gn];
            #pragma unroll
            for (int r = 0; r < 4; ++r) {
                int gm = gm_base + r;
                if (gm < M) {
                    float v = tanh_fast(acc[im][in][r] + bv);
                    C[(size_t)gm * N + gn] = f2bf(v);
                }
            }
        }
    }
}

// ---------- GEMM (bf16 A): m97-style, XOR-8 swizzle ----------
template<bool TANH>
__global__ __launch_bounds__(256) void gemm_bt(
    const unsigned short* __restrict__ A, const unsigned short* __restrict__ B,
    const float* __restrict__ bias, unsigned short* __restrict__ C,
    int M, int N, int K)
{
    __shared__ __align__(16) short As[TM][BK];
    __shared__ __align__(16) short Bs[TM][BK];

    const int tid  = threadIdx.x;
    const int wave = tid >> 6;
    const int lane = tid & 63;
    const int m0 = blockIdx.x * TM;
    const int n0 = blockIdx.y * TN;
    const int wm = (wave >> 1) * 64;
    const int wn = (wave & 1) * 64;
    const int lm = lane & 15;
    const int quad = lane >> 4;

    const int srow = lane >> 3;
    const int scol = ((lane & 7) ^ srow) * 8;
    const int cc0 = (quad ^ (lm & 7)) * 8;
    const int cc1 = ((4 + quad) ^ (lm & 7)) * 8;

    f32x4 acc[4][4] = {};

    for (int k0 = 0; k0 < K; k0 += BK) {
        #pragma unroll
        for (int i = 0; i < 4; ++i) {
            int row = wave * 32 + i * 8;
            int gr = m0 + row + srow; if (gr >= M) gr = M - 1;
            GLD16(A + (size_t)gr * K + k0 + scol, &As[row][0]);
            GLD16(B + (size_t)(n0 + row + srow) * K + k0 + scol, &Bs[row][0]);
        }
        __syncthreads();

        #pragma unroll
        for (int ks = 0; ks < BK; ks += 32) {
            const int cc = (ks == 0) ? cc0 : cc1;
            short8 af[4], bf_[4];
            #pragma unroll
            for (int i = 0; i < 4; ++i) {
                af[i]  = *(const short8*)&As[wm + i * 16 + lm][cc];
                bf_[i] = *(const short8*)&Bs[wn + i * 16 + lm][cc];
            }
            #pragma unroll
            for (int im = 0; im < 4; ++im)
                #pragma unroll
                for (int in = 0; in < 4; ++in)
                    acc[im][in] = __builtin_amdgcn_mfma_f32_16x16x32_bf16(
                        af[im], bf_[in], acc[im][in], 0, 0, 0);
        }
        __syncthreads();
    }

    #pragma unroll
    for (int im = 0; im < 4; ++im) {
        int gm_base = m0 + wm + im * 16 + quad * 4;
        #pragma unroll
        for (int in = 0; in < 4; ++in) {
            int gn = n0 + wn + in * 16 + lm;
            float bv = bias[gn];
            #pragma unroll
            for (int r = 0; r < 4; ++r) {
                int gm = gm_base + r;
                if (gm < M) {
                    float v = acc[im][in][r] + bv;
                    if (TANH) v = tanh_fast(v);
                    C[(size_t)gm * N + gn] = f2bf(v);
                }
            }
        }
    }
}

// ---------- edge histogram: packed (degAll<<32 | degGated) ----------
__global__ __launch_bounds__(256) void edge_hist(
    const int* __restrict__ ei, const float* __restrict__ alpha,
    unsigned long long* __restrict__ deg, int E)
{
    int e = blockIdx.x * 256 + threadIdx.x;
    if (e >= E) return;
    int dst = ei[E + e];
    float gate = 2.0f * fmaxf(alpha[e] - 0.5f, 0.0f);
    atomicAdd(&deg[dst], 0x100000000ULL | (gate > 0.0f ? 1ULL : 0ULL));
}

// ---------- scan step 1: per-block (1024) exclusive scan; writes rowptr+cursor ----------
__global__ __launch_bounds__(256) void scan1(
    const unsigned long long* __restrict__ deg, int* __restrict__ rowptr,
    int* __restrict__ cursor, int* __restrict__ partials, int N)
{
    __shared__ int sums[256];
    int base = blockIdx.x * 1024 + threadIdx.x * 4;
    int v[4];
    #pragma unroll
    for (int i = 0; i < 4; ++i) {
        int idx = base + i;
        v[i] = (idx < N) ? (int)(deg[idx] & 0xffffffffULL) : 0;
    }
    int s = v[0] + v[1] + v[2] + v[3];
    sums[threadIdx.x] = s;
    __syncthreads();
    for (int off = 1; off < 256; off <<= 1) {
        int t = (threadIdx.x >= off) ? sums[threadIdx.x - off] : 0;
        __syncthreads();
        sums[threadIdx.x] += t;
        __syncthreads();
    }
    int excl = sums[threadIdx.x] - s;
    if (threadIdx.x == 255) partials[blockIdx.x] = sums[255];
    int run = excl;
    #pragma unroll
    for (int i = 0; i < 4; ++i) {
        int idx = base + i;
        if (idx < N) { rowptr[idx] = run; cursor[idx] = run; }
        run += v[i];
    }
}

// ---------- scan step 2: exclusive-scan the block partials ----------
__global__ __launch_bounds__(256) void scan2(int* __restrict__ partials, int nb)
{
    __shared__ int s[256];
    int v = (threadIdx.x < nb) ? partials[threadIdx.x] : 0;
    s[threadIdx.x] = v;
    __syncthreads();
    for (int off = 1; off < 256; off <<= 1) {
        int t = (threadIdx.x >= off) ? s[threadIdx.x - off] : 0;
        __syncthreads();
        s[threadIdx.x] += t;
        __syncthreads();
    }
    partials[threadIdx.x] = s[threadIdx.x] - v;   // exclusive
}

// ---------- fill CSR with gated edges (block offset folded in) ----------
__global__ __launch_bounds__(256) void edge_fill(
    const int* __restrict__ ei, const float* __restrict__ alpha,
    int* __restrict__ cursor, const int* __restrict__ partials,
    int2* __restrict__ recs, int E)
{
    int e = blockIdx.x * 256 + threadIdx.x;
    if (e >= E) return;
    float gate = 2.0f * fmaxf(alpha[e] - 0.5f, 0.0f);
    if (gate > 0.0f) {
        int dst = ei[E + e];
        int src = ei[e];
        int pos = atomicAdd(&cursor[dst], 1) + partials[dst >> 10];
        recs[pos] = make_int2(src, __float_as_int(gate));
    }
}

// ---------- per-node gather + mean: one wave/node, 2 edges/iter ----------
__global__ __launch_bounds__(256) void node_gather(
    const unsigned short* __restrict__ h, const unsigned long long* __restrict__ deg,
    const int* __restrict__ rowptr, const int* __restrict__ partials,
    const int2* __restrict__ recs, float* __restrict__ out, int N)
{
    int wave = threadIdx.x >> 6;
    int lane = threadIdx.x & 63;
    int node = blockIdx.x * 4 + wave;
    if (node >= N) return;
    unsigned long long d = deg[node];
    int dAll  = __builtin_amdgcn_readfirstlane((int)(d >> 32));
    int dG    = __builtin_amdgcn_readfirstlane((int)(d & 0xffffffffULL));
    int start = __builtin_amdgcn_readfirstlane(rowptr[node] + partials[node >> 10]);
    int half = lane >> 5, hl = lane & 31;
    float ax = 0.f, ay = 0.f, az = 0.f, aw = 0.f;
    for (int j = 0; j < dG; j += 2) {
        int jj = j + half;
        int idx = start + (jj < dG ? jj : dG - 1);
        int2 rec = recs[idx];
        float gate = (jj < dG) ? __int_as_float(rec.y) : 0.0f;
        uint2 u = *(const uint2*)(h + ((size_t)rec.x << 7) + hl * 4);
        ax += bf2f((unsigned short)(u.x & 0xffffu)) * gate;
        ay += bf2f((unsigned short)(u.x >> 16)) * gate;
        az += bf2f((unsigned short)(u.y & 0xffffu)) * gate;
        aw += bf2f((unsigned short)(u.y >> 16)) * gate;
    }
    ax += __shfl_down(ax, 32);
    ay += __shfl_down(ay, 32);
    az += __shfl_down(az, 32);
    aw += __shfl_down(aw, 32);
    if (half == 0) {
        float inv = 1.0f / fmaxf((float)dAll, 1.0f);
        *(float4*)(out + ((size_t)node << 7) + hl * 4) =
            make_float4(ax * inv, ay * inv, az * inv, aw * inv);
    }
}

// ---------- launch ----------
extern "C" void kernel_launch(void* const* d_in, const int* in_sizes, int n_in,
                              void* d_out, int out_size, void* d_ws, size_t ws_size,
                              hipStream_t stream) {
    const float* x     = (const float*)d_in[0];
    const float* alpha = (const float*)d_in[1];
    const int*   ei    = (const int*)d_in[2];
    const float* W1 = (const float*)d_in[4];
    const float* b1 = (const float*)d_in[5];
    const float* W2 = (const float*)d_in[6];
    const float* b2 = (const float*)d_in[7];
    const float* W3 = (const float*)d_in[8];
    const float* b3 = (const float*)d_in[9];
    float* out = (float*)d_out;

    const int N = in_sizes[0] / 256;   // 100000
    const int E = in_sizes[1];         // 640000
    const int IN = 256, H1 = 512, H2 = 256, D = 128;

    char* ws = (char*)d_ws;
    size_t off = 0;
    auto take = [&](size_t bytes) { char* p = ws + off; off = (off + bytes + 255) & ~(size_t)255; return p; };
    unsigned short* h1bf = (unsigned short*)take((size_t)N * H1 * 2);   // reused as CSR after GEMM2
    unsigned short* h2bf = (unsigned short*)take((size_t)N * H2 * 2);
    unsigned short* hbf  = (unsigned short*)take((size_t)N * D  * 2);
    unsigned short* w1bf = (unsigned short*)take((size_t)H1 * IN * 2);
    unsigned short* w2bf = (unsigned short*)take((size_t)H2 * H1 * 2);
    unsigned short* w3bf = (unsigned short*)take((size_t)D  * H2 * 2);

    // CSR scratch carved from h1bf region (dead after GEMM2)
    char* cbase = (char*)h1bf;
    size_t coff = 0;
    auto ctake = [&](size_t bytes) { char* p = cbase + coff; coff = (coff + bytes + 255) & ~(size_t)255; return p; };
    unsigned long long* deg = (unsigned long long*)ctake((size_t)N * 8);
    int*  rowptr   = (int*)ctake((size_t)N * 4);
    int*  cursor   = (int*)ctake((size_t)N * 4);
    int*  partials = (int*)ctake(256 * 4);
    int2* recs     = (int2*)ctake((size_t)E * 8);

    dim3 blk(256);

    // ---- MLP ----
    cast_weights<<<(294912 / 4 + 255) / 256, blk, 0, stream>>>(W1, W2, W3, w1bf, w2bf, w3bf);

    const int mblk = (N + TM - 1) / TM;
    gemm_a32_bt    <<<dim3(mblk, H1 / TN), blk, 0, stream>>>(x,    w1bf, b1, h1bf, N, H1, IN);
    gemm_bt<true > <<<dim3(mblk, H2 / TN), blk, 0, stream>>>(h1bf, w2bf, b2, h2bf, N, H2, H1);
    gemm_bt<false> <<<dim3(mblk, D / TN),  blk, 0, stream>>>(h2bf, w3bf, b3, hbf,  N, D,  H2);

    // ---- CSR build (h1bf region now dead) ----
    hipMemsetAsync(deg, 0, (size_t)N * 8, stream);
    edge_hist<<<(E + 255) / 256, blk, 0, stream>>>(ei, alpha, deg, E);
    const int nb1 = (N + 1023) / 1024;   // 98
    scan1<<<nb1, blk, 0, stream>>>(deg, rowptr, cursor, partials, N);
    scan2<<<1, blk, 0, stream>>>(partials, nb1);
    edge_fill<<<(E + 255) / 256, blk, 0, stream>>>(ei, alpha, cursor, partials, recs, E);

    // ---- gather + mean ----
    node_gather<<<(N + 3) / 4, blk, 0, stream>>>(hbf, deg, rowptr, partials, recs, out, N);
}

// Round 6
// 410.939 us; speedup vs baseline: 1.0734x; 1.0734x over previous
//
#include <hip/hip_runtime.h>

// ---------- helpers ----------
typedef __attribute__((ext_vector_type(8))) short short8;
typedef __attribute__((ext_vector_type(4))) float f32x4;

__device__ __forceinline__ unsigned short f2bf(float f) {
    union { float f; unsigned u; } v; v.f = f;
    unsigned r = v.u + 0x7FFFu + ((v.u >> 16) & 1u);   // RNE
    return (unsigned short)(r >> 16);
}
__device__ __forceinline__ float bf2f(unsigned short h) {
    union { unsigned u; float f; } v; v.u = ((unsigned)h) << 16;
    return v.f;
}

// fast tanh: 1 v_exp_f32 + 1 v_rcp_f32. rel err ~1e-5 << bf16 ulp.
__device__ __forceinline__ float tanh_fast(float x) {
    float xc = fminf(fmaxf(x, -9.0f), 9.0f);
    float t  = __expf(2.0f * xc);
    return (t - 1.0f) * __builtin_amdgcn_rcpf(t + 1.0f);
}

#define GLD16(gptr, lptr)                                                     \
    __builtin_amdgcn_global_load_lds(                                         \
        (const __attribute__((address_space(1))) unsigned int*)(gptr),        \
        (__attribute__((address_space(3))) unsigned int*)(lptr), 16, 0, 0)

// ---------- merged casts: x|W1|W2|W3 f32 -> bf16 ----------
__global__ __launch_bounds__(256) void cast_all(
    const float* __restrict__ x,  unsigned short* __restrict__ xbf,
    const float* __restrict__ W1, unsigned short* __restrict__ w1bf,
    const float* __restrict__ W2, unsigned short* __restrict__ w2bf,
    const float* __restrict__ W3, unsigned short* __restrict__ w3bf,
    int xq)   // x quads = N*256/4
{
    int t = blockIdx.x * 256 + threadIdx.x;
    const float* s; unsigned short* d; int q;
    if (t < xq) { s = x; d = xbf; q = t; }
    else {
        int u = t - xq;
        if (u < 32768)      { s = W1; d = w1bf; q = u; }
        else if (u < 65536) { s = W2; d = w2bf; q = u - 32768; }
        else if (u < 73728) { s = W3; d = w3bf; q = u - 65536; }
        else return;
    }
    int base = q * 4;
    float4 v = *(const float4*)(s + base);
    unsigned long long p =
        (unsigned long long)f2bf(v.x)
      | ((unsigned long long)f2bf(v.y) << 16)
      | ((unsigned long long)f2bf(v.z) << 32)
      | ((unsigned long long)f2bf(v.w) << 48);
    *(unsigned long long*)(d + base) = p;
}

#define TM 128
#define TN 128
#define BK 64

// ---------- GEMM1 (proven R4 structure): bf16 A, B^T, tanh fused ----------
__global__ __launch_bounds__(256) void gemm_bt(
    const unsigned short* __restrict__ A, const unsigned short* __restrict__ B,
    const float* __restrict__ bias, unsigned short* __restrict__ C,
    int M, int N, int K)
{
    __shared__ __align__(16) short As[TM][BK];
    __shared__ __align__(16) short Bs[TM][BK];

    const int tid  = threadIdx.x;
    const int wave = tid >> 6;
    const int lane = tid & 63;
    const int m0 = blockIdx.x * TM;
    const int n0 = blockIdx.y * TN;
    const int wm = (wave >> 1) * 64;
    const int wn = (wave & 1) * 64;
    const int lm = lane & 15;
    const int quad = lane >> 4;

    const int srow = lane >> 3;
    const int scol = ((lane & 7) ^ srow) * 8;
    const int cc0 = (quad ^ (lm & 7)) * 8;
    const int cc1 = ((4 + quad) ^ (lm & 7)) * 8;

    f32x4 acc[4][4] = {};

    for (int k0 = 0; k0 < K; k0 += BK) {
        #pragma unroll
        for (int i = 0; i < 4; ++i) {
            int row = wave * 32 + i * 8;
            int gr = m0 + row + srow; if (gr >= M) gr = M - 1;
            GLD16(A + (size_t)gr * K + k0 + scol, &As[row][0]);
            GLD16(B + (size_t)(n0 + row + srow) * K + k0 + scol, &Bs[row][0]);
        }
        __syncthreads();

        #pragma unroll
        for (int ks = 0; ks < BK; ks += 32) {
            const int cc = (ks == 0) ? cc0 : cc1;
            short8 af[4], bf_[4];
            #pragma unroll
            for (int i = 0; i < 4; ++i) {
                af[i]  = *(const short8*)&As[wm + i * 16 + lm][cc];
                bf_[i] = *(const short8*)&Bs[wn + i * 16 + lm][cc];
            }
            #pragma unroll
            for (int im = 0; im < 4; ++im)
                #pragma unroll
                for (int in = 0; in < 4; ++in)
                    acc[im][in] = __builtin_amdgcn_mfma_f32_16x16x32_bf16(
                        af[im], bf_[in], acc[im][in], 0, 0, 0);
        }
        __syncthreads();
    }

    #pragma unroll
    for (int im = 0; im < 4; ++im) {
        int gm_base = m0 + wm + im * 16 + quad * 4;
        #pragma unroll
        for (int in = 0; in < 4; ++in) {
            int gn = n0 + wn + in * 16 + lm;
            float bv = bias[gn];
            #pragma unroll
            for (int r = 0; r < 4; ++r) {
                int gm = gm_base + r;
                if (gm < M) {
                    float v = tanh_fast(acc[im][in][r] + bv);
                    C[(size_t)gm * N + gn] = f2bf(v);
                }
            }
        }
    }
}

// ---------- fused GEMM2+GEMM3 ----------
// Per block (64 rows): h2 = tanh(h1[64x512] @ W2[256x512]^T + b2) -> LDS;
// h = h2 @ W3[128x256]^T + b3 -> global bf16. h2 never touches global.
__global__ __launch_bounds__(256) void gemm23(
    const unsigned short* __restrict__ h1, const unsigned short* __restrict__ W2,
    const float* __restrict__ b2, const unsigned short* __restrict__ W3,
    const float* __restrict__ b3, unsigned short* __restrict__ hout, int M)
{
    __shared__ __align__(16) short As[64][64];     // 8 KB  (h1 k-tiles)
    __shared__ __align__(16) short Bs[256][64];    // 32 KB (W2 k-tiles; reused for W3)
    __shared__ __align__(16) short h2s[64][264];   // 33 KB (+8 pad: 16B-aligned rows)

    const int tid  = threadIdx.x;
    const int wave = tid >> 6;
    const int lane = tid & 63;
    const int m0 = blockIdx.x * 64;
    const int wm = (wave >> 1) * 32;
    const int lm = lane & 15;
    const int quad = lane >> 4;
    const int srow = lane >> 3;
    const int scol = ((lane & 7) ^ srow) * 8;
    const int cc0 = (quad ^ (lm & 7)) * 8;
    const int cc1 = ((4 + quad) ^ (lm & 7)) * 8;

    // ---- phase A: h2 = tanh(h1 @ W2^T + b2) ----
    {
        const int wn = (wave & 1) * 128;
        f32x4 acc[2][8] = {};
        for (int k0 = 0; k0 < 512; k0 += 64) {
            #pragma unroll
            for (int i = 0; i < 2; ++i) {             // A: 64 rows (16/wave)
                int r0 = wave * 16 + i * 8;
                int gr = m0 + r0 + srow; if (gr >= M) gr = M - 1;
                GLD16(h1 + (size_t)gr * 512 + k0 + scol, &As[r0][0]);
            }
            #pragma unroll
            for (int i = 0; i < 8; ++i) {             // W2: 256 rows (64/wave)
                int r0 = wave * 64 + i * 8;
                GLD16(W2 + (size_t)(r0 + srow) * 512 + k0 + scol, &Bs[r0][0]);
            }
            __syncthreads();
            #pragma unroll
            for (int ks = 0; ks < 64; ks += 32) {
                const int cc = (ks == 0) ? cc0 : cc1;
                short8 af[2], bf_[8];
                #pragma unroll
                for (int i = 0; i < 2; ++i) af[i]  = *(const short8*)&As[wm + i * 16 + lm][cc];
                #pragma unroll
                for (int i = 0; i < 8; ++i) bf_[i] = *(const short8*)&Bs[wn + i * 16 + lm][cc];
                #pragma unroll
                for (int im = 0; im < 2; ++im)
                    #pragma unroll
                    for (int in = 0; in < 8; ++in)
                        acc[im][in] = __builtin_amdgcn_mfma_f32_16x16x32_bf16(
                            af[im], bf_[in], acc[im][in], 0, 0, 0);
            }
            __syncthreads();
        }
        // epilogue -> LDS h2s
        #pragma unroll
        for (int im = 0; im < 2; ++im) {
            int rb = wm + im * 16 + quad * 4;
            #pragma unroll
            for (int in = 0; in < 8; ++in) {
                int col = wn + in * 16 + lm;
                float bv = b2[col];
                #pragma unroll
                for (int r = 0; r < 4; ++r)
                    h2s[rb + r][col] = (short)f2bf(tanh_fast(acc[im][in][r] + bv));
            }
        }
    }
    __syncthreads();

    // ---- phase B: h = h2s @ W3^T + b3 ----
    {
        const int wn = (wave & 1) * 64;
        short (*Bs3)[64] = (short(*)[64])&Bs[0][0];
        f32x4 acc[2][4] = {};
        for (int k0 = 0; k0 < 256; k0 += 64) {
            #pragma unroll
            for (int i = 0; i < 4; ++i) {             // W3: 128 rows (32/wave)
                int r0 = wave * 32 + i * 8;
                GLD16(W3 + (size_t)(r0 + srow) * 256 + k0 + scol, &Bs3[r0][0]);
            }
            __syncthreads();
            #pragma unroll
            for (int ks = 0; ks < 64; ks += 32) {
                const int cc = (ks == 0) ? cc0 : cc1;
                short8 af[2], bf_[4];
                #pragma unroll
                for (int i = 0; i < 2; ++i)
                    af[i] = *(const short8*)&h2s[wm + i * 16 + lm][k0 + ks + quad * 8];
                #pragma unroll
                for (int i = 0; i < 4; ++i)
                    bf_[i] = *(const short8*)&Bs3[wn + i * 16 + lm][cc];
                #pragma unroll
                for (int im = 0; im < 2; ++im)
                    #pragma unroll
                    for (int in = 0; in < 4; ++in)
                        acc[im][in] = __builtin_amdgcn_mfma_f32_16x16x32_bf16(
                            af[im], bf_[in], acc[im][in], 0, 0, 0);
            }
            __syncthreads();
        }
        #pragma unroll
        for (int im = 0; im < 2; ++im) {
            int gm_base = m0 + wm + im * 16 + quad * 4;
            #pragma unroll
            for (int in = 0; in < 4; ++in) {
                int gn = wn + in * 16 + lm;
                float bv = b3[gn];
                #pragma unroll
                for (int r = 0; r < 4; ++r) {
                    int gm = gm_base + r;
                    if (gm < M)
                        hout[(size_t)gm * 128 + gn] = f2bf(acc[im][in][r] + bv);
                }
            }
        }
    }
}

// ---------- edge histogram: packed (degAll<<32 | degGated) ----------
__global__ __launch_bounds__(256) void edge_hist(
    const int* __restrict__ ei, const float* __restrict__ alpha,
    unsigned long long* __restrict__ deg, int E)
{
    int e = blockIdx.x * 256 + threadIdx.x;
    if (e >= E) return;
    int dst = ei[E + e];
    float gate = 2.0f * fmaxf(alpha[e] - 0.5f, 0.0f);
    atomicAdd(&deg[dst], 0x100000000ULL | (gate > 0.0f ? 1ULL : 0ULL));
}

// ---------- scan step 1: per-block (1024) exclusive scan; writes rowptr+cursor ----------
__global__ __launch_bounds__(256) void scan1(
    const unsigned long long* __restrict__ deg, int* __restrict__ rowptr,
    int* __restrict__ cursor, int* __restrict__ partials, int N)
{
    __shared__ int sums[256];
    int base = blockIdx.x * 1024 + threadIdx.x * 4;
    int v[4];
    #pragma unroll
    for (int i = 0; i < 4; ++i) {
        int idx = base + i;
        v[i] = (idx < N) ? (int)(deg[idx] & 0xffffffffULL) : 0;
    }
    int s = v[0] + v[1] + v[2] + v[3];
    sums[threadIdx.x] = s;
    __syncthreads();
    for (int off = 1; off < 256; off <<= 1) {
        int t = (threadIdx.x >= off) ? sums[threadIdx.x - off] : 0;
        __syncthreads();
        sums[threadIdx.x] += t;
        __syncthreads();
    }
    int excl = sums[threadIdx.x] - s;
    if (threadIdx.x == 255) partials[blockIdx.x] = sums[255];
    int run = excl;
    #pragma unroll
    for (int i = 0; i < 4; ++i) {
        int idx = base + i;
        if (idx < N) { rowptr[idx] = run; cursor[idx] = run; }
        run += v[i];
    }
}

// ---------- scan step 2: exclusive-scan the block partials ----------
__global__ __launch_bounds__(256) void scan2(int* __restrict__ partials, int nb)
{
    __shared__ int s[256];
    int v = (threadIdx.x < nb) ? partials[threadIdx.x] : 0;
    s[threadIdx.x] = v;
    __syncthreads();
    for (int off = 1; off < 256; off <<= 1) {
        int t = (threadIdx.x >= off) ? s[threadIdx.x - off] : 0;
        __syncthreads();
        s[threadIdx.x] += t;
        __syncthreads();
    }
    partials[threadIdx.x] = s[threadIdx.x] - v;   // exclusive
}

// ---------- fill CSR with gated edges (block offset folded in) ----------
__global__ __launch_bounds__(256) void edge_fill(
    const int* __restrict__ ei, const float* __restrict__ alpha,
    int* __restrict__ cursor, const int* __restrict__ partials,
    int2* __restrict__ recs, int E)
{
    int e = blockIdx.x * 256 + threadIdx.x;
    if (e >= E) return;
    float gate = 2.0f * fmaxf(alpha[e] - 0.5f, 0.0f);
    if (gate > 0.0f) {
        int dst = ei[E + e];
        int src = ei[e];
        int pos = atomicAdd(&cursor[dst], 1) + partials[dst >> 10];
        recs[pos] = make_int2(src, __float_as_int(gate));
    }
}

// ---------- per-node gather + mean: one wave/node, 4 edges/iter ----------
__global__ __launch_bounds__(256) void node_gather(
    const unsigned short* __restrict__ h, const unsigned long long* __restrict__ deg,
    const int* __restrict__ rowptr, const int* __restrict__ partials,
    const int2* __restrict__ recs, float* __restrict__ out, int N)
{
    int wave = threadIdx.x >> 6;
    int lane = threadIdx.x & 63;
    int node = blockIdx.x * 4 + wave;
    if (node >= N) return;
    unsigned long long d = deg[node];
    int dAll  = __builtin_amdgcn_readfirstlane((int)(d >> 32));
    int dG    = __builtin_amdgcn_readfirstlane((int)(d & 0xffffffffULL));
    int start = __builtin_amdgcn_readfirstlane(rowptr[node] + partials[node >> 10]);
    int qw = lane >> 4, ql = lane & 15;     // quarter-wave per edge; 16 lanes x 16B = row
    float a[8] = {};
    for (int j = 0; j < dG; j += 4) {
        int jj = j + qw;
        int idx = start + (jj < dG ? jj : dG - 1);
        int2 rec = recs[idx];
        float gate = (jj < dG) ? __int_as_float(rec.y) : 0.0f;
        uint4 u = *(const uint4*)(h + ((size_t)rec.x << 7) + ql * 8);
        a[0] += bf2f((unsigned short)(u.x & 0xffffu)) * gate;
        a[1] += bf2f((unsigned short)(u.x >> 16)) * gate;
        a[2] += bf2f((unsigned short)(u.y & 0xffffu)) * gate;
        a[3] += bf2f((unsigned short)(u.y >> 16)) * gate;
        a[4] += bf2f((unsigned short)(u.z & 0xffffu)) * gate;
        a[5] += bf2f((unsigned short)(u.z >> 16)) * gate;
        a[6] += bf2f((unsigned short)(u.w & 0xffffu)) * gate;
        a[7] += bf2f((unsigned short)(u.w >> 16)) * gate;
    }
    #pragma unroll
    for (int i = 0; i < 8; ++i) {
        a[i] += __shfl_xor(a[i], 16);
        a[i] += __shfl_xor(a[i], 32);
    }
    if (qw == 0) {
        float inv = 1.0f / fmaxf((float)dAll, 1.0f);
        float* op = out + ((size_t)node << 7) + ql * 8;
        *(float4*)(op)     = make_float4(a[0] * inv, a[1] * inv, a[2] * inv, a[3] * inv);
        *(float4*)(op + 4) = make_float4(a[4] * inv, a[5] * inv, a[6] * inv, a[7] * inv);
    }
}

// ---------- launch ----------
extern "C" void kernel_launch(void* const* d_in, const int* in_sizes, int n_in,
                              void* d_out, int out_size, void* d_ws, size_t ws_size,
                              hipStream_t stream) {
    const float* x     = (const float*)d_in[0];
    const float* alpha = (const float*)d_in[1];
    const int*   ei    = (const int*)d_in[2];
    const float* W1 = (const float*)d_in[4];
    const float* b1 = (const float*)d_in[5];
    const float* W2 = (const float*)d_in[6];
    const float* b2 = (const float*)d_in[7];
    const float* W3 = (const float*)d_in[8];
    const float* b3 = (const float*)d_in[9];
    float* out = (float*)d_out;

    const int N = in_sizes[0] / 256;   // 100000
    const int E = in_sizes[1];         // 640000
    const int IN = 256, H1 = 512, D = 128;

    char* ws = (char*)d_ws;
    size_t off = 0;
    auto take = [&](size_t bytes) { char* p = ws + off; off = (off + bytes + 255) & ~(size_t)255; return p; };
    unsigned short* xbf  = (unsigned short*)take((size_t)N * IN * 2);
    unsigned short* h1bf = (unsigned short*)take((size_t)N * H1 * 2);   // CSR aliased after gemm23
    unsigned short* hbf  = (unsigned short*)take((size_t)N * D  * 2);
    unsigned short* w1bf = (unsigned short*)take((size_t)H1 * IN * 2);
    unsigned short* w2bf = (unsigned short*)take((size_t)256 * H1 * 2);
    unsigned short* w3bf = (unsigned short*)take((size_t)D * 256 * 2);

    // CSR scratch aliased into h1bf (h1 dead after gemm23; CSR used after)
    char* cbase = (char*)h1bf;
    size_t coff = 0;
    auto ctake = [&](size_t bytes) { char* p = cbase + coff; coff = (coff + bytes + 255) & ~(size_t)255; return p; };
    unsigned long long* deg = (unsigned long long*)ctake((size_t)N * 8);
    int*  rowptr   = (int*)ctake((size_t)N * 4);
    int*  cursor   = (int*)ctake((size_t)N * 4);
    int*  partials = (int*)ctake(256 * 4);
    int2* recs     = (int2*)ctake((size_t)E * 8);

    dim3 blk(256);

    // ---- MLP ----
    const int xq = N * IN / 4;                      // 6.4M quads
    const int castN = xq + 73728;
    cast_all<<<(castN + 255) / 256, blk, 0, stream>>>(x, xbf, W1, w1bf, W2, w2bf, W3, w3bf, xq);

    const int mblk = (N + TM - 1) / TM;             // 782
    gemm_bt<<<dim3(mblk, H1 / TN), blk, 0, stream>>>(xbf, w1bf, b1, h1bf, N, H1, IN);
    gemm23<<<(N + 63) / 64, blk, 0, stream>>>(h1bf, w2bf, b2, w3bf, b3, hbf, N);

    // ---- CSR build (h1bf region now dead) ----
    hipMemsetAsync(deg, 0, (size_t)N * 8, stream);
    edge_hist<<<(E + 255) / 256, blk, 0, stream>>>(ei, alpha, deg, E);
    const int nb1 = (N + 1023) / 1024;   // 98
    scan1<<<nb1, blk, 0, stream>>>(deg, rowptr, cursor, partials, N);
    scan2<<<1, blk, 0, stream>>>(partials, nb1);
    edge_fill<<<(E + 255) / 256, blk, 0, stream>>>(ei, alpha, cursor, partials, recs, E);

    // ---- gather + mean ----
    node_gather<<<(N + 3) / 4, blk, 0, stream>>>(hbf, deg, rowptr, partials, recs, out, N);
}